// Round 12
// baseline (2198.027 us; speedup 1.0000x reference)
//
#include <hip/hip_runtime.h>
#include <hip/hip_bf16.h>

#define B 64
#define T 256
#define IN 512
#define H 1024
#define L 6

#define NBLK 192            // 3 layer-pairs * 64 col tiles
#define TPB 512             // 8 waves = 4 m-tiles x 2 K-halves
#define NCOL 16
#define TILES_PER_L 64
#define WROWB 3072          // bytes per W row (1536 bf16), XOR-swizzled
#define W_BYTES (32 * WROWB)           // 2 layers x 16 cols = 98304
#define BUF0 W_BYTES
#define BUF1 (W_BYTES + 32768)
#define SMEM_BYTES (W_BYTES + 65536)   // 163840 = 160 KiB

typedef __bf16 bf16x8 __attribute__((ext_vector_type(8)));
typedef __bf16 bf16x4 __attribute__((ext_vector_type(4)));
typedef float f32x4 __attribute__((ext_vector_type(4)));

// ---------------------------------------------------------------------------
// prep: x [B,T,I] fp32 -> xbf [T,B,I] bf16 ; h0 fp32 -> hb0 bf16
// ---------------------------------------------------------------------------
__global__ void prep_kernel(const float* __restrict__ x,
                            const float* __restrict__ h0,
                            __bf16* __restrict__ xbf,
                            __bf16* __restrict__ hb0) {
    const int N4x = B * T * (IN / 4);
    const int N4h = L * B * (H / 4);
    int stride = gridDim.x * blockDim.x;
    for (int u = blockIdx.x * blockDim.x + threadIdx.x; u < N4x + N4h; u += stride) {
        if (u < N4x) {
            int b = u / (T * (IN / 4));
            int r = u % (T * (IN / 4));
            int t = r / (IN / 4), c4 = r % (IN / 4);
            float4 v = reinterpret_cast<const float4*>(x)[u];
            bf16x4 o = {(__bf16)v.x, (__bf16)v.y, (__bf16)v.z, (__bf16)v.w};
            *reinterpret_cast<bf16x4*>(xbf + ((size_t)t * B + b) * IN + c4 * 4) = o;
        } else {
            int j = u - N4x;
            float4 v = reinterpret_cast<const float4*>(h0)[j];
            bf16x4 o = {(__bf16)v.x, (__bf16)v.y, (__bf16)v.z, (__bf16)v.w};
            *reinterpret_cast<bf16x4*>(hb0 + (size_t)j * 4) = o;
        }
    }
}

// ---------------------------------------------------------------------------
// Persistent layer-PAIR kernel: block owns 16 cols of layers lA=bid/64 and
// lB=lA+3 (independent recurrences). Per period t: run step t of A then B;
// producer->consumer latency of each layer hides under the other's work.
// W both layers in LDS (96 KB swizzled); 8 waves = 4 m-tiles x 2 K-halves;
// K-split partials reduced via LDS; h + flags via IF (sc0 sc1, r7 protocol).
// ---------------------------------------------------------------------------
__global__ __launch_bounds__(TPB, 2)
void rnn_kernel(const __bf16* __restrict__ xbf,   // [T][B][IN]
                const float*  __restrict__ wih,   // [L][H][IN] fp32
                const float*  __restrict__ whh,   // [L][H][H]  fp32
                const float*  __restrict__ bih,
                const float*  __restrict__ bhh,
                __bf16* __restrict__ hb0,         // [L][B][H]
                __bf16* __restrict__ hb1,
                float*  __restrict__ out,
                unsigned* __restrict__ flags) {   // [L*64]
    extern __shared__ char smem[];

    const int lA   = blockIdx.x / TILES_PER_L;        // 0..2
    const int lB   = lA + 3;
    const int rank = blockIdx.x % TILES_PER_L;
    const int n0   = rank * NCOL;
    const int tid  = threadIdx.x;
    const int lane = tid & 63;
    const int wave = tid >> 6;
    const int mi   = wave & 3;      // m-tile: rows mi*16..+15
    const int kh   = wave >> 2;     // K-half
    const int lr16 = lane & 15;
    const int lk   = lane >> 4;

    const int g = n0 + lr16;                          // output column
    const float bvA = bih[lA * H + g] + bhh[lA * H + g];
    const float bvB = bih[lB * H + g] + bhh[lB * H + g];

    // ---- one-time: W both layers -> LDS (rows 0..15 = A, 16..31 = B) -------
    for (int u = tid; u < 32 * 192; u += TPB) {
        int r = u / 192;               // LDS W row
        int c = u % 192;               // 16B unit
        int S = r >> 4, col = r & 15;
        int li = S ? lB : lA;
        int k0 = c * 8;
        const float* src = (k0 < IN)
            ? wih + ((size_t)(li * H + n0 + col)) * IN + k0
            : whh + ((size_t)(li * H + n0 + col)) * H + (k0 - IN);
        float4 f0 = *reinterpret_cast<const float4*>(src);
        float4 f1 = *reinterpret_cast<const float4*>(src + 4);
        bf16x8 o = {(__bf16)f0.x, (__bf16)f0.y, (__bf16)f0.z, (__bf16)f0.w,
                    (__bf16)f1.x, (__bf16)f1.y, (__bf16)f1.z, (__bf16)f1.w};
        *reinterpret_cast<bf16x8*>(smem + (size_t)r * WROWB +
                                   ((c ^ (r & 7)) << 4)) = o;
    }

    const char* wrA = smem + (size_t)lr16 * WROWB;      // this lane's W row, layer A
    const char* wrB = wrA + 16 * WROWB;                 // layer B
    const int arow  = mi * 16 + lr16;                   // A-tile row this lane reads
    const int axr   = arow & 7;
    const int bxr   = lr16 & 7;

    const int row0 = tid >> 5;      // staging row base (0..15)
    const int c0   = tid & 31;      // staging 16B unit (0..31)
    char* wb = smem + row0 * 512 + ((c0 ^ (row0 & 7)) << 4);  // + BUF, + j*8192

#define VMWAIT(N) do { asm volatile("s_waitcnt vmcnt(" #N ")" ::: "memory");    \
                       __builtin_amdgcn_sched_barrier(0); } while (0)

    // 16 h-quad loads for one layer (chunk-major), IF-coherent, early-clobber
#define ISSUE16(HS, Q0,Q1,Q2,Q3,Q4,Q5,Q6,Q7,Q8,Q9,Q10,Q11,Q12,Q13,Q14,Q15)     \
    { const char* h0_ = (HS) + (size_t)(row0 +  0) * 2048 + c0 * 16;            \
      const char* h1_ = (HS) + (size_t)(row0 + 16) * 2048 + c0 * 16;            \
      const char* h2_ = (HS) + (size_t)(row0 + 32) * 2048 + c0 * 16;            \
      const char* h3_ = (HS) + (size_t)(row0 + 48) * 2048 + c0 * 16;            \
      asm volatile(                                                             \
        "global_load_dwordx4 %[q0],  %[a0], off sc0 sc1\n\t"                    \
        "global_load_dwordx4 %[q1],  %[a1], off sc0 sc1\n\t"                    \
        "global_load_dwordx4 %[q2],  %[a2], off sc0 sc1\n\t"                    \
        "global_load_dwordx4 %[q3],  %[a3], off sc0 sc1\n\t"                    \
        "global_load_dwordx4 %[q4],  %[a0], off offset:512 sc0 sc1\n\t"         \
        "global_load_dwordx4 %[q5],  %[a1], off offset:512 sc0 sc1\n\t"         \
        "global_load_dwordx4 %[q6],  %[a2], off offset:512 sc0 sc1\n\t"         \
        "global_load_dwordx4 %[q7],  %[a3], off offset:512 sc0 sc1\n\t"         \
        "global_load_dwordx4 %[q8],  %[a0], off offset:1024 sc0 sc1\n\t"        \
        "global_load_dwordx4 %[q9],  %[a1], off offset:1024 sc0 sc1\n\t"        \
        "global_load_dwordx4 %[q10], %[a2], off offset:1024 sc0 sc1\n\t"        \
        "global_load_dwordx4 %[q11], %[a3], off offset:1024 sc0 sc1\n\t"        \
        "global_load_dwordx4 %[q12], %[a0], off offset:1536 sc0 sc1\n\t"        \
        "global_load_dwordx4 %[q13], %[a1], off offset:1536 sc0 sc1\n\t"        \
        "global_load_dwordx4 %[q14], %[a2], off offset:1536 sc0 sc1\n\t"        \
        "global_load_dwordx4 %[q15], %[a3], off offset:1536 sc0 sc1"            \
        : [q0]"=&v"(Q0), [q1]"=&v"(Q1), [q2]"=&v"(Q2), [q3]"=&v"(Q3),           \
          [q4]"=&v"(Q4), [q5]"=&v"(Q5), [q6]"=&v"(Q6), [q7]"=&v"(Q7),           \
          [q8]"=&v"(Q8), [q9]"=&v"(Q9), [q10]"=&v"(Q10), [q11]"=&v"(Q11),       \
          [q12]"=&v"(Q12), [q13]"=&v"(Q13), [q14]"=&v"(Q14), [q15]"=&v"(Q15)    \
        : [a0]"v"(h0_), [a1]"v"(h1_), [a2]"v"(h2_), [a3]"v"(h3_)                \
        : "memory"); }

#define WRITE4(BOFF, D0, D1, D2, D3)                                            \
    { char* w_ = wb + (BOFF);                                                   \
      *reinterpret_cast<f32x4*>(w_)         = D0;                               \
      *reinterpret_cast<f32x4*>(w_ + 8192)  = D1;                               \
      *reinterpret_cast<f32x4*>(w_ + 16384) = D2;                               \
      *reinterpret_cast<f32x4*>(w_ + 24576) = D3; }

    // x chunk (512B/row) staged via cached loads; CHB = chunk byte offset
#define STAGE_XC(SRC, CHB, BOFF)                                                \
    { _Pragma("unroll")                                                         \
      for (int j_ = 0; j_ < 4; ++j_) {                                          \
          f32x4 v_ = *reinterpret_cast<const f32x4*>(                           \
              (SRC) + (size_t)(row0 + 16 * j_) * 1024 + (CHB) + c0 * 16);       \
          *reinterpret_cast<f32x4*>(wb + (BOFF) + j_ * 8192) = v_;              \
      } }

    // 8 MFMAs over one staged chunk; WR = W row ptr, WUB = W unit base
#define MFMA_CH(BOFF, WR, WUB, ACCE, ACCO)                                      \
    { _Pragma("unroll")                                                         \
      for (int ss_ = 0; ss_ < 8; ++ss_) {                                       \
          bf16x8 af_ = *reinterpret_cast<const bf16x8*>(                        \
              smem + (BOFF) + arow * 512 + (((ss_ * 4 + lk) ^ axr) << 4));      \
          bf16x8 bw_ = *reinterpret_cast<const bf16x8*>(                        \
              (WR) + ((((WUB) + ss_ * 4 + lk) ^ bxr) << 4));                    \
          if (ss_ & 1) ACCO = __builtin_amdgcn_mfma_f32_16x16x32_bf16(          \
                                  af_, bw_, ACCO, 0, 0, 0);                     \
          else         ACCE = __builtin_amdgcn_mfma_f32_16x16x32_bf16(          \
                                  af_, bw_, ACCE, 0, 0, 0);                     \
      } }

    const f32x4 zero = {0.f, 0.f, 0.f, 0.f};
    f32x4 aAE = zero, aAO = zero, aBE = zero, aBO = zero;

    f32x4 qa0,qa1,qa2,qa3,qa4,qa5,qa6,qa7,qa8,qa9,qa10,qa11,qa12,qa13,qa14,qa15;
    f32x4 qb0,qb1,qb2,qb3,qb4,qb5,qb6,qb7,qb8,qb9,qb10,qb11,qb12,qb13,qb14,qb15;

    // ---- prologue: x-proj t=0 for both layers (kh0 waves compute) ----------
    {
        const char* xb = (const char*)xbf;
        STAGE_XC(xb, 0, BUF0);
        STAGE_XC(xb, 512, BUF1);
        __syncthreads();                 // also flushes W fill
        if (kh == 0) { MFMA_CH(BUF0, wrA, 0, aAE, aAO);
                       MFMA_CH(BUF1, wrA, 32, aAE, aAO); }
        __syncthreads();
        STAGE_XC(xb, 0, BUF0);           // restage for layer B (same x!)
        STAGE_XC(xb, 512, BUF1);
        __syncthreads();
        if (kh == 0) { MFMA_CH(BUF0, wrB, 0, aBE, aBO);
                       MFMA_CH(BUF1, wrB, 32, aBE, aBO); }
    }

    for (int t = 0; t < T; ++t) {
        const __bf16* hcur = (t & 1) ? hb1 : hb0;
        __bf16*       hnxt = (t & 1) ? hb0 : hb1;

        // P: wave0 polls both layers' 64 flags (one lane each)
        if (t > 0 && wave == 0) {
            const unsigned* fa = flags + lA * TILES_PER_L + lane;
            const unsigned* fb = flags + lB * TILES_PER_L + lane;
            unsigned f1, f2;
            for (;;) {
                asm volatile(
                    "global_load_dword %0, %2, off sc0 sc1\n\t"
                    "global_load_dword %1, %3, off sc0 sc1\n\t"
                    "s_waitcnt vmcnt(0)"
                    : "=&v"(f1), "=&v"(f2) : "v"(fa), "v"(fb) : "memory");
                if (__all((int)(f1 >= (unsigned)t)) &
                    __all((int)(f2 >= (unsigned)t))) break;
                __builtin_amdgcn_s_sleep(1);
            }
        }
        __syncthreads();   // P-bar (also: x-proj reads of bufs done)

        // issue ALL 32 h quads: A then B (vmcnt drains descend 28..0)
        const char* hqA = (const char*)(hcur + (size_t)lA * B * H);
        const char* hqB = (const char*)(hcur + (size_t)lB * B * H);
        ISSUE16(hqA, qa0,qa1,qa2,qa3,qa4,qa5,qa6,qa7,
                     qa8,qa9,qa10,qa11,qa12,qa13,qa14,qa15);
        ISSUE16(hqB, qb0,qb1,qb2,qb3,qb4,qb5,qb6,qb7,
                     qb8,qb9,qb10,qb11,qb12,qb13,qb14,qb15);

        // ---- layer A: 4 chunks (h W-units 64..191) -------------------------
        VMWAIT(28); WRITE4(BUF0, qa0, qa1, qa2, qa3);
        __syncthreads();
        if (kh == 0) MFMA_CH(BUF0, wrA, 64, aAE, aAO);
        VMWAIT(24); WRITE4(BUF1, qa4, qa5, qa6, qa7);
        __syncthreads();
        if (kh == 1) MFMA_CH(BUF1, wrA, 96, aAE, aAO);
        VMWAIT(20); WRITE4(BUF0, qa8, qa9, qa10, qa11);
        __syncthreads();
        if (kh == 1) MFMA_CH(BUF0, wrA, 128, aAE, aAO);
        VMWAIT(16); WRITE4(BUF1, qa12, qa13, qa14, qa15);
        __syncthreads();
        if (kh == 1) MFMA_CH(BUF1, wrA, 160, aAE, aAO);
        // ---- layer B ---------------------------------------------------------
        VMWAIT(12); WRITE4(BUF0, qb0, qb1, qb2, qb3);
        __syncthreads();
        if (kh == 0) MFMA_CH(BUF0, wrB, 64, aBE, aBO);
        VMWAIT(8);  WRITE4(BUF1, qb4, qb5, qb6, qb7);
        __syncthreads();
        if (kh == 1) MFMA_CH(BUF1, wrB, 96, aBE, aBO);
        VMWAIT(4);  WRITE4(BUF0, qb8, qb9, qb10, qb11);
        __syncthreads();
        if (kh == 1) MFMA_CH(BUF0, wrB, 128, aBE, aBO);
        VMWAIT(0);  WRITE4(BUF1, qb12, qb13, qb14, qb15);
        __syncthreads();
        if (kh == 1) MFMA_CH(BUF1, wrB, 160, aBE, aBO);

        // ---- K-split reduction via LDS (region = BUF0, 16 KB) --------------
        {
            f32x4 pA = aAE + aAO, pB = aBE + aBO;
            char* pp = smem + BUF0 + kh * 4096 + mi * 1024 + lane * 16;
            *reinterpret_cast<f32x4*>(pp)        = pA;
            *reinterpret_cast<f32x4*>(pp + 8192) = pB;
        }
        __syncthreads();
        f32x4 fvA, fvB;
        {
            const char* rp = smem + BUF0 + mi * 1024 + lane * 16;
            fvA = *reinterpret_cast<const f32x4*>(rp)
                + *reinterpret_cast<const f32x4*>(rp + 4096);
            fvB = *reinterpret_cast<const f32x4*>(rp + 8192)
                + *reinterpret_cast<const f32x4*>(rp + 12288);
        }

        // ---- epilogue: rows j = 2kh, 2kh+1 of this lane's 4-row group ------
        const int j0 = 2 * kh;
        const int brow = mi * 16 + lk * 4 + j0;
        float vA0 = fvA[j0]     + bvA; vA0 = (vA0 >= 0.f) ? vA0 : 0.01f * vA0;
        float vA1 = fvA[j0 + 1] + bvA; vA1 = (vA1 >= 0.f) ? vA1 : 0.01f * vA1;
        float vB0 = fvB[j0]     + bvB; vB0 = (vB0 >= 0.f) ? vB0 : 0.01f * vB0;
        float vB1 = fvB[j0 + 1] + bvB; vB1 = (vB1 >= 0.f) ? vB1 : 0.01f * vB1;
        {
            union { __bf16 b; unsigned short u; } cv;
            uint32_t sA0, sA1, sB0, sB1;
            cv.b = (__bf16)vA0; sA0 = cv.u;  cv.b = (__bf16)vA1; sA1 = cv.u;
            cv.b = (__bf16)vB0; sB0 = cv.u;  cv.b = (__bf16)vB1; sB1 = cv.u;
            const char* pA = (const char*)(hnxt + ((size_t)(lA * B + brow)) * H + g);
            const char* pB = (const char*)(hnxt + ((size_t)(lB * B + brow)) * H + g);
            asm volatile(
                "global_store_short %[a0], %[v0], off sc0 sc1\n\t"
                "global_store_short %[a0], %[v1], off offset:2048 sc0 sc1\n\t"
                "global_store_short %[a1], %[v2], off sc0 sc1\n\t"
                "global_store_short %[a1], %[v3], off offset:2048 sc0 sc1"
                :: [a0]"v"(pA), [a1]"v"(pB),
                   [v0]"v"(sA0), [v1]"v"(sA1), [v2]"v"(sB0), [v3]"v"(sB1)
                : "memory");
        }
        if (lB == L - 1) {   // layer B is the output layer for lpair==2
            out[((size_t)brow * T + t) * H + g]       = vB0;
            out[((size_t)(brow + 1) * T + t) * H + g] = vB1;
        }
        if (t == T - 1) {
            float* hT = out + (size_t)B * T * H;
            hT[((size_t)(lA * B + brow)) * H + g]     = vA0;
            hT[((size_t)(lA * B + brow + 1)) * H + g] = vA1;
            hT[((size_t)(lB * B + brow)) * H + g]     = vB0;
            hT[((size_t)(lB * B + brow + 1)) * H + g] = vB1;
        }
        VMWAIT(0);         // h stores at IF
        __syncthreads();   // whole block done (also frees BUF0 partials)
        if (tid == 0) {
            unsigned val = (unsigned)(t + 1);
            unsigned* fpA = flags + lA * TILES_PER_L + rank;
            unsigned* fpB = flags + lB * TILES_PER_L + rank;
            asm volatile(
                "global_store_dword %0, %2, off sc0 sc1\n\t"
                "global_store_dword %1, %2, off sc0 sc1"
                :: "v"(fpA), "v"(fpB), "v"(val) : "memory");
        }

        // ---- shadow: x-proj(t+1) for both layers ---------------------------
        if (t + 1 < T) {
            aAE = zero; aAO = zero; aBE = zero; aBO = zero;
            const char* xb = (const char*)(xbf + (size_t)(t + 1) * B * IN);
            STAGE_XC(xb, 0, BUF0);
            STAGE_XC(xb, 512, BUF1);
            __syncthreads();
            if (kh == 0) { MFMA_CH(BUF0, wrA, 0, aAE, aAO);
                           MFMA_CH(BUF1, wrA, 32, aAE, aAO); }
            __syncthreads();
            STAGE_XC(xb, 0, BUF0);
            STAGE_XC(xb, 512, BUF1);
            __syncthreads();
            if (kh == 0) { MFMA_CH(BUF0, wrB, 0, aBE, aBO);
                           MFMA_CH(BUF1, wrB, 32, aBE, aBO); }
        }
    }
}

// ---------------------------------------------------------------------------
extern "C" void kernel_launch(void* const* d_in, const int* in_sizes, int n_in,
                              void* d_out, int out_size, void* d_ws, size_t ws_size,
                              hipStream_t stream) {
    const float* x   = (const float*)d_in[0];
    const float* h0  = (const float*)d_in[1];
    const float* wih = (const float*)d_in[2];
    const float* whh = (const float*)d_in[3];
    const float* bih = (const float*)d_in[4];
    const float* bhh = (const float*)d_in[5];
    float* out = (float*)d_out;

    char* ws = (char*)d_ws;
    __bf16* xbf = (__bf16*)ws;                                   // 16 MB
    __bf16* hb0 = (__bf16*)(ws + (size_t)16777216);              // 768 KB
    __bf16* hb1 = (__bf16*)(ws + (size_t)16777216 + 786432);     // 768 KB
    unsigned* flags = (unsigned*)(ws + (size_t)16777216 + 2 * 786432); // 1.5 KB

    (void)hipMemsetAsync(flags, 0, L * TILES_PER_L * sizeof(unsigned), stream);
    prep_kernel<<<2048, 256, 0, stream>>>(x, h0, xbf, hb0);

    static bool attr_done = []() {
        hipFuncSetAttribute((const void*)rnn_kernel,
                            hipFuncAttributeMaxDynamicSharedMemorySize,
                            SMEM_BYTES);
        return true;
    }();
    (void)attr_done;

    rnn_kernel<<<NBLK, TPB, SMEM_BYTES, stream>>>(
        xbf, wih, whh, bih, bhh, hb0, hb1, out, flags);
}

// Round 13
// 1085.343 us; speedup vs baseline: 2.0252x; 2.0252x over previous
//
#include <hip/hip_runtime.h>
#include <hip/hip_bf16.h>

#define B 64
#define T 256
#define IN 512
#define H 1024
#define L 6

#define NBLK 192            // 6 layers * 32 col tiles
#define TPB 512             // 8 waves = 2 row-tiles x 4 K-slices
#define NCOL 32
#define TILES_PER_L 32
#define FB_LAYER 131072     // h frag buffer per layer: 64 frags * 2048 B
#define XF_T 65536          // x frag buffer per t: 32 frags * 2048 B

typedef __bf16 bf16x8 __attribute__((ext_vector_type(8)));
typedef __bf16 bf16x4 __attribute__((ext_vector_type(4)));
typedef float f32x4  __attribute__((ext_vector_type(4)));
typedef float f32x16 __attribute__((ext_vector_type(16)));

// ---------------------------------------------------------------------------
// prep: frag-major formatting.
//  xF[t][fk=i>>4][row=b][half=(i>>3)&1][e=i&7]  (bf16)
//  F0[l][fk=g>>4][row=b][half][e] from h0
// Element byte addr: fk*2048 + b*32 + half*16 + e*2.
// ---------------------------------------------------------------------------
__global__ void prep_kernel(const float* __restrict__ x,
                            const float* __restrict__ h0,
                            char* __restrict__ xF,
                            char* __restrict__ F0) {
    const int N4x = B * T * (IN / 4);
    const int N4h = L * B * (H / 4);
    int stride = gridDim.x * blockDim.x;
    for (int u = blockIdx.x * blockDim.x + threadIdx.x; u < N4x + N4h; u += stride) {
        if (u < N4x) {
            int b = u / (T * (IN / 4));
            int r = u % (T * (IN / 4));
            int t = r / (IN / 4), i = (r % (IN / 4)) * 4;
            float4 v = reinterpret_cast<const float4*>(x)[u];
            bf16x4 o = {(__bf16)v.x, (__bf16)v.y, (__bf16)v.z, (__bf16)v.w};
            size_t dst = (size_t)t * XF_T + (size_t)(i >> 4) * 2048
                       + b * 32 + ((i >> 3) & 1) * 16 + (i & 7) * 2;
            *reinterpret_cast<bf16x4*>(xF + dst) = o;
        } else {
            int j = u - N4x;
            int l = j / (B * (H / 4));
            int r = j % (B * (H / 4));
            int b = r / (H / 4), g = (r % (H / 4)) * 4;
            float4 v = reinterpret_cast<const float4*>(h0)[j];
            bf16x4 o = {(__bf16)v.x, (__bf16)v.y, (__bf16)v.z, (__bf16)v.w};
            size_t dst = (size_t)l * FB_LAYER + (size_t)(g >> 4) * 2048
                       + b * 32 + ((g >> 3) & 1) * 16 + (g & 7) * 2;
            *reinterpret_cast<bf16x4*>(F0 + dst) = o;
        }
    }
}

// ---------------------------------------------------------------------------
// Persistent per-(layer, col-tile) kernel, frag-major h exchange.
// 8 waves = 2 row-tiles (th) x 4 K-slices (ks). mfma 32x32x16.
// W in VGPRs (24 frags). A-frags loaded DIRECTLY from frag-major F buffers
// (coalesced 1KB/instr) -- no LDS staging, 2 barriers/step.
// LDS only for the K-split reduction (32 KB). Flags: IF-scope, per-wave poll.
// ---------------------------------------------------------------------------
__global__ __launch_bounds__(TPB, 1)
void rnn_kernel(const char* __restrict__ xF,
                const float* __restrict__ wih,   // [L][H][IN] fp32
                const float* __restrict__ whh,   // [L][H][H]  fp32
                const float* __restrict__ bih,
                const float* __restrict__ bhh,
                char* __restrict__ F0,           // h frag buffers (parity)
                char* __restrict__ F1,
                float* __restrict__ out,
                unsigned* __restrict__ flags) {  // [L*32]
    __shared__ char smem[32768];                 // K-split reduce only

    const int l    = blockIdx.x >> 5;
    const int rank = blockIdx.x & 31;
    const int n0   = rank * NCOL;
    const int tid  = threadIdx.x;
    const int lane = tid & 63;
    const int wave = tid >> 6;
    const int th   = wave & 1;      // row tile: rows th*32..+31
    const int ks   = wave >> 1;     // K-slice 0..3
    const int l31  = lane & 31;
    const int l5   = lane >> 5;
    const int hi8  = l5 * 8;

    const int g = n0 + l31;                       // output column
    const float bv = bih[l * H + g] + bhh[l * H + g];

    // ---- one-time: this wave's 24 W B-frags -> VGPRs (r11-verified map) ----
    bf16x8 w[24];
    #pragma unroll
    for (int f = 0; f < 8; ++f) {                 // x-part (K=128 slice)
        int kg = (ks & 1) * 256 + (ks >> 1) * 128 + f * 16 + hi8;
        const float* s = wih + ((size_t)(l * H + g)) * IN + kg;
        float4 a = *reinterpret_cast<const float4*>(s);
        float4 b = *reinterpret_cast<const float4*>(s + 4);
        w[f] = bf16x8{(__bf16)a.x, (__bf16)a.y, (__bf16)a.z, (__bf16)a.w,
                      (__bf16)b.x, (__bf16)b.y, (__bf16)b.z, (__bf16)b.w};
    }
    #pragma unroll
    for (int k2 = 0; k2 < 16; ++k2) {             // h-part (K=256 slice)
        int kg = ks * 256 + k2 * 16 + hi8;
        const float* s = whh + ((size_t)(l * H + g)) * H + kg;
        float4 a = *reinterpret_cast<const float4*>(s);
        float4 b = *reinterpret_cast<const float4*>(s + 4);
        w[8 + k2] = bf16x8{(__bf16)a.x, (__bf16)a.y, (__bf16)a.z, (__bf16)a.w,
                           (__bf16)b.x, (__bf16)b.y, (__bf16)b.z, (__bf16)b.w};
    }

    // per-lane offset within a frag: A[row=th*32+l31][k-half l5]
    const size_t foff = (size_t)(th * 32 + l31) * 32 + l5 * 16;

#define VMWAIT(N) do { asm volatile("s_waitcnt vmcnt(" #N ")" ::: "memory");    \
                       __builtin_amdgcn_sched_barrier(0); } while (0)

    // 4 frag loads: base P, frags at +0, +2048, +4096, +6144 (two base regs)
#define ISSUE4(P, D0,D1,D2,D3)                                                  \
    { const char* p0_ = (P); const char* p1_ = (P) + 4096;                       \
      asm volatile(                                                             \
        "global_load_dwordx4 %[d0], %[a0], off sc0 sc1\n\t"                     \
        "global_load_dwordx4 %[d1], %[a0], off offset:2048 sc0 sc1\n\t"         \
        "global_load_dwordx4 %[d2], %[a1], off sc0 sc1\n\t"                     \
        "global_load_dwordx4 %[d3], %[a1], off offset:2048 sc0 sc1"             \
        : [d0]"=&v"(D0), [d1]"=&v"(D1), [d2]"=&v"(D2), [d3]"=&v"(D3)            \
        : [a0]"v"(p0_), [a1]"v"(p1_) : "memory"); }

#define MH(QQ, K2)                                                              \
    do { if ((K2) & 1) accO = __builtin_amdgcn_mfma_f32_32x32x16_bf16(          \
                                  QQ, w[8 + (K2)], accO, 0, 0, 0);              \
         else          accE = __builtin_amdgcn_mfma_f32_32x32x16_bf16(          \
                                  QQ, w[8 + (K2)], accE, 0, 0, 0); } while (0)

    f32x16 accE, accO;
    #pragma unroll
    for (int i = 0; i < 16; ++i) { accE[i] = 0.f; accO[i] = 0.f; }

    bf16x8 q0,q1,q2,q3,q4,q5,q6,q7,q8,q9,q10,q11,q12,q13,q14,q15;

    // x frag base offset for this wave (frags of its K-slice of x)
    const size_t xslice = (size_t)((ks & 1) * 16 + (ks >> 1) * 8) * 2048 + foff;

    // ---- prologue: x-projection for t=0 (cached frag loads + mfma) ---------
    {
        const char* xb = xF + xslice;   // t = 0
        #pragma unroll
        for (int f2 = 0; f2 < 8; ++f2) {
            bf16x8 af = *reinterpret_cast<const bf16x8*>(xb + f2 * 2048);
            if (f2 & 1) accO = __builtin_amdgcn_mfma_f32_32x32x16_bf16(
                                   af, w[f2], accO, 0, 0, 0);
            else        accE = __builtin_amdgcn_mfma_f32_32x32x16_bf16(
                                   af, w[f2], accE, 0, 0, 0);
        }
        __builtin_amdgcn_sched_barrier(0);
    }

    for (int t = 0; t < T; ++t) {
        char* Fcur = (t & 1) ? F1 : F0;
        char* Fnxt = (t & 1) ? F0 : F1;

        // P: EVERY wave polls the 32 sibling flags (self-releasing, no bar)
        if (t > 0) {
            const unsigned* fa = flags + l * TILES_PER_L + l31;
            unsigned f;
            for (;;) {
                asm volatile("global_load_dword %0, %1, off sc0 sc1\n\t"
                             "s_waitcnt vmcnt(0)"
                             : "=&v"(f) : "v"(fa) : "memory");
                if (__all((int)(f >= (unsigned)t))) break;
                __builtin_amdgcn_s_sleep(1);
            }
        }
        __builtin_amdgcn_sched_barrier(0);

        // ---- issue this wave's 16 h frag loads (coalesced 1KB each) --------
        const char* hb = Fcur + (size_t)l * FB_LAYER + (size_t)ks * 32768 + foff;
        ISSUE4(hb,         q0,  q1,  q2,  q3);
        ISSUE4(hb + 8192,  q4,  q5,  q6,  q7);
        ISSUE4(hb + 16384, q8,  q9,  q10, q11);
        ISSUE4(hb + 24576, q12, q13, q14, q15);

        VMWAIT(12); MH(q0, 0);  MH(q1, 1);  MH(q2, 2);  MH(q3, 3);
        VMWAIT(8);  MH(q4, 4);  MH(q5, 5);  MH(q6, 6);  MH(q7, 7);
        VMWAIT(4);  MH(q8, 8);  MH(q9, 9);  MH(q10,10); MH(q11,11);
        VMWAIT(0);  MH(q12,12); MH(q13,13); MH(q14,14); MH(q15,15);

        // ---- K-split reduction through LDS (r11-verified mapping) ----------
        {
            f32x16 pw = accE + accO;
            char* pp = smem + wave * 4096 + lane * 16;
            *reinterpret_cast<f32x4*>(pp)        = f32x4{pw[0],pw[1],pw[2],pw[3]};
            *reinterpret_cast<f32x4*>(pp + 1024) = f32x4{pw[4],pw[5],pw[6],pw[7]};
            *reinterpret_cast<f32x4*>(pp + 2048) = f32x4{pw[8],pw[9],pw[10],pw[11]};
            *reinterpret_cast<f32x4*>(pp + 3072) = f32x4{pw[12],pw[13],pw[14],pw[15]};
        }
        __syncthreads();                          // BAR1: partials visible
        f32x4 fv;
        {
            const char* rp = smem + th * 4096 + ks * 1024 + lane * 16;
            f32x4 p0 = *reinterpret_cast<const f32x4*>(rp);
            f32x4 p1 = *reinterpret_cast<const f32x4*>(rp + 8192);
            f32x4 p2 = *reinterpret_cast<const f32x4*>(rp + 16384);
            f32x4 p3 = *reinterpret_cast<const f32x4*>(rp + 24576);
            fv = p0 + p1 + p2 + p3;
        }

        // ---- epilogue: rows rbase..+3, col g; scatter into Fnxt frag layout -
        const int rbase = 8 * ks + 4 * l5 + 32 * th;
        float vv[4];
        #pragma unroll
        for (int j = 0; j < 4; ++j) {
            float v = fv[j] + bv;
            vv[j] = (v >= 0.f) ? v : 0.01f * v;
        }
        {
            union { __bf16 b; unsigned short u; } cv;
            uint32_t s0, s1, s2, s3;
            cv.b = (__bf16)vv[0]; s0 = cv.u;
            cv.b = (__bf16)vv[1]; s1 = cv.u;
            cv.b = (__bf16)vv[2]; s2 = cv.u;
            cv.b = (__bf16)vv[3]; s3 = cv.u;
            // byte addr of (row=rbase, col=g): fk*2048 + row*32 + half*16 + e*2
            const char* p0 = Fnxt + (size_t)l * FB_LAYER
                           + (size_t)(g >> 4) * 2048 + (size_t)rbase * 32
                           + ((g >> 3) & 1) * 16 + (g & 7) * 2;
            asm volatile(
                "global_store_short %[a], %[v0], off sc0 sc1\n\t"
                "global_store_short %[a], %[v1], off offset:32 sc0 sc1\n\t"
                "global_store_short %[a], %[v2], off offset:64 sc0 sc1\n\t"
                "global_store_short %[a], %[v3], off offset:96 sc0 sc1"
                :: [a]"v"(p0),
                   [v0]"v"(s0), [v1]"v"(s1), [v2]"v"(s2), [v3]"v"(s3)
                : "memory");
        }
        #pragma unroll
        for (int j = 0; j < 4; ++j) {
            int b = rbase + j;
            if (l == L - 1) out[((size_t)b * T + t) * H + g] = vv[j];
            if (t == T - 1)
                out[(size_t)B * T * H + ((size_t)(l * B + b)) * H + g] = vv[j];
        }
        VMWAIT(0);         // h scatter (and out) stores drained to IF
        __syncthreads();   // BAR2: whole block's h_{t+1} visible; LDS reusable
        if (tid == 0) {
            unsigned val = (unsigned)(t + 1);
            unsigned* fp = flags + l * TILES_PER_L + rank;
            asm volatile("global_store_dword %0, %1, off sc0 sc1"
                         :: "v"(fp), "v"(val) : "memory");
        }

        // ---- shadow: x-projection for t+1 (cached frag loads) --------------
        if (t + 1 < T) {
            #pragma unroll
            for (int i = 0; i < 16; ++i) { accE[i] = 0.f; accO[i] = 0.f; }
            const char* xb = xF + (size_t)(t + 1) * XF_T + xslice;
            #pragma unroll
            for (int f2 = 0; f2 < 8; ++f2) {
                bf16x8 af = *reinterpret_cast<const bf16x8*>(xb + f2 * 2048);
                if (f2 & 1) accO = __builtin_amdgcn_mfma_f32_32x32x16_bf16(
                                       af, w[f2], accO, 0, 0, 0);
                else        accE = __builtin_amdgcn_mfma_f32_32x32x16_bf16(
                                       af, w[f2], accE, 0, 0, 0);
            }
            __builtin_amdgcn_sched_barrier(0);
        }
    }
}

// ---------------------------------------------------------------------------
extern "C" void kernel_launch(void* const* d_in, const int* in_sizes, int n_in,
                              void* d_out, int out_size, void* d_ws, size_t ws_size,
                              hipStream_t stream) {
    const float* x   = (const float*)d_in[0];
    const float* h0  = (const float*)d_in[1];
    const float* wih = (const float*)d_in[2];
    const float* whh = (const float*)d_in[3];
    const float* bih = (const float*)d_in[4];
    const float* bhh = (const float*)d_in[5];
    float* out = (float*)d_out;

    char* ws = (char*)d_ws;
    char* xF = ws;                                        // 16 MB
    char* F0 = ws + (size_t)16777216;                     // 768 KB
    char* F1 = ws + (size_t)16777216 + 786432;            // 768 KB
    unsigned* flags = (unsigned*)(ws + (size_t)16777216 + 2 * 786432);

    (void)hipMemsetAsync(flags, 0, L * TILES_PER_L * sizeof(unsigned), stream);
    prep_kernel<<<2048, 256, 0, stream>>>(x, h0, xF, F0);

    rnn_kernel<<<NBLK, TPB, 0, stream>>>(
        xF, wih, whh, bih, bhh, F0, F1, out, flags);
}